// Round 1
// 196.131 us; speedup vs baseline: 1.0100x; 1.0100x over previous
//
#include <hip/hip_runtime.h>

// Embedding gather: out[b,s,:] = weight[token_ids[b,s],:]
// BATCH=4, SEQ=4096, DIM=1024, VOCAB=32000, fp32.
// Roofline: 64 MiB streamed writes + ~52 MiB unique weight-row reads
//   ≈ 119 MiB HBM traffic → ~19 us at 6.4 TB/s. Kernel-local budget.
//
// This version vs previous (one token/wave, plain stores):
//  - 2 tokens per wave: 8 independent 16B loads in flight before any
//    dependent store (more MLP), half the wave count (8192 waves).
//  - NONTEMPORAL stores for the output: out is written once and never
//    re-read; nt keeps the 64 MiB output stream from write-allocating in
//    the 4 MiB/XCD L2s, preserving weight rows so the ~22% duplicate
//    token reads hit L2/L3 instead of refetching.

#define DIM 1024
#define F4_PER_ROW (DIM / 4)          // 256 float4 per row
#define TOKENS_PER_WAVE 2
#define WAVES_PER_BLOCK 4             // 256 threads
#define TOKENS_PER_BLOCK (TOKENS_PER_WAVE * WAVES_PER_BLOCK)  // 8

typedef float f32x4 __attribute__((ext_vector_type(4)));

__global__ __launch_bounds__(256) void embedding_gather_kernel(
    const int* __restrict__ token_ids,
    const f32x4* __restrict__ weight,   // [VOCAB, DIM/4]
    f32x4* __restrict__ out,            // [N_TOKENS, DIM/4]
    int n_tokens)
{
    const int wave = threadIdx.x >> 6;        // 0..3
    const int lane = threadIdx.x & 63;        // 0..63
    const int t0 = (blockIdx.x * WAVES_PER_BLOCK + wave) * TOKENS_PER_WAVE;
    if (t0 >= n_tokens) return;

    // Wave-uniform token ids (compiler readfirstlane's these).
    const int tokA = token_ids[t0];
    const int tokB = token_ids[t0 + 1];

    const f32x4* __restrict__ srcA = weight + (size_t)tokA * F4_PER_ROW;
    const f32x4* __restrict__ srcB = weight + (size_t)tokB * F4_PER_ROW;
    f32x4* __restrict__ dstA = out + (size_t)t0 * F4_PER_ROW;
    f32x4* __restrict__ dstB = dstA + F4_PER_ROW;

    // 8 independent coalesced 1 KiB/wave loads — all issued before any
    // store consumes them (compiler batches vmcnt waits).
    f32x4 a0 = srcA[lane];
    f32x4 a1 = srcA[lane + 64];
    f32x4 a2 = srcA[lane + 128];
    f32x4 a3 = srcA[lane + 192];
    f32x4 b0 = srcB[lane];
    f32x4 b1 = srcB[lane + 64];
    f32x4 b2 = srcB[lane + 128];
    f32x4 b3 = srcB[lane + 192];

    // Streaming (nt) stores: bypass L2 allocation for the write-once output.
    __builtin_nontemporal_store(a0, &dstA[lane]);
    __builtin_nontemporal_store(a1, &dstA[lane + 64]);
    __builtin_nontemporal_store(a2, &dstA[lane + 128]);
    __builtin_nontemporal_store(a3, &dstA[lane + 192]);
    __builtin_nontemporal_store(b0, &dstB[lane]);
    __builtin_nontemporal_store(b1, &dstB[lane + 64]);
    __builtin_nontemporal_store(b2, &dstB[lane + 128]);
    __builtin_nontemporal_store(b3, &dstB[lane + 192]);
}

extern "C" void kernel_launch(void* const* d_in, const int* in_sizes, int n_in,
                              void* d_out, int out_size, void* d_ws, size_t ws_size,
                              hipStream_t stream) {
    const int* token_ids = (const int*)d_in[0];       // [4, 4096] int32
    const f32x4* weight = (const f32x4*)d_in[1];      // [32000, 1024] f32
    f32x4* out = (f32x4*)d_out;                       // [4, 4096, 1024] f32

    const int n_tokens = in_sizes[0];                 // 16384
    dim3 grid((n_tokens + TOKENS_PER_BLOCK - 1) / TOKENS_PER_BLOCK);
    dim3 block(WAVES_PER_BLOCK * 64);
    embedding_gather_kernel<<<grid, block, 0, stream>>>(token_ids, weight, out, n_tokens);
}